// Round 1
// baseline (1178.656 us; speedup 1.0000x reference)
//
#include <hip/hip_runtime.h>
#include <hip/hip_bf16.h>

// Problem constants
#define S_LEN 4096
#define EMB   1024
#define NH    16
#define HD    64
#define WIN   256
#define SCALE 0.125f

typedef __attribute__((ext_vector_type(8))) short short8;   // 8 bf16 (4 VGPRs)
typedef __attribute__((ext_vector_type(4))) float f32x4;    // 4 fp32 acc

// ---------------------------------------------------------------- cast f32->bf16
__global__ __launch_bounds__(256) void cast_f32_bf16(const float* __restrict__ in,
                                                     unsigned short* __restrict__ out,
                                                     int n) {
    int i = blockIdx.x * blockDim.x + threadIdx.x;
    int stride = gridDim.x * blockDim.x;
    for (; i < n; i += stride) {
        __hip_bfloat16 b = __float2bfloat16(in[i]);
        out[i] = *reinterpret_cast<unsigned short*>(&b);
    }
}

// ---------------------------------------------------------------- bf16 MFMA GEMM
// C[M,N] (f32) = A[M,K] (bf16) @ B[K,N] (bf16). M,N multiples of 64, K of 32.
// block = 256 threads (4 waves); 64x64 tile; BK=32; each wave does a 32x32 quadrant.
#define AS_STR 56   // 56 elems = 112 B row stride: 16B-aligned, 2-way bank alias (free)

__global__ __launch_bounds__(256) void gemm_bf16(const unsigned short* __restrict__ A,
                                                 const unsigned short* __restrict__ B,
                                                 float* __restrict__ C,
                                                 int M, int N, int K) {
    __shared__ unsigned short As[64 * AS_STR];
    __shared__ unsigned short Bs[64 * AS_STR];   // transposed: Bs[n][k]

    const int tid  = threadIdx.x;
    const int lane = tid & 63;
    const int wid  = tid >> 6;
    const int quad = lane >> 4;
    const int l16  = lane & 15;

    const int m0 = blockIdx.y * 64;
    const int n0 = blockIdx.x * 64;

    const int m_off = (wid & 1) * 32;
    const int n_off = (wid >> 1) * 32;

    // A stage mapping: thread -> (row 0..63, kchunk 0..3)
    const int a_row = tid >> 2;
    const int a_kc  = (tid & 3) * 8;
    // B stage mapping: thread -> (k 0..31, nchunk 0..7)
    const int b_k  = tid >> 3;
    const int b_n0 = (tid & 7) * 8;

    f32x4 acc[2][2];
    #pragma unroll
    for (int i = 0; i < 2; ++i)
        #pragma unroll
        for (int j = 0; j < 2; ++j)
            acc[i][j] = (f32x4){0.f, 0.f, 0.f, 0.f};

    const int ksteps = K >> 5;
    for (int bk = 0; bk < ksteps; ++bk) {
        __syncthreads();
        // stage A: 16B per thread, coalesced
        {
            const uint4 av = *reinterpret_cast<const uint4*>(
                A + (size_t)(m0 + a_row) * K + bk * 32 + a_kc);
            *reinterpret_cast<uint4*>(&As[a_row * AS_STR + a_kc]) = av;
        }
        // stage B transposed: 16B coalesced read, scalar scattered LDS writes
        {
            union { uint4 v; unsigned short u[8]; } t;
            t.v = *reinterpret_cast<const uint4*>(
                B + (size_t)(bk * 32 + b_k) * N + n0 + b_n0);
            #pragma unroll
            for (int j = 0; j < 8; ++j)
                Bs[(b_n0 + j) * AS_STR + b_k] = t.u[j];
        }
        __syncthreads();

        short8 af[2], bf[2];
        #pragma unroll
        for (int i = 0; i < 2; ++i)
            af[i] = *reinterpret_cast<const short8*>(
                &As[(m_off + i * 16 + l16) * AS_STR + quad * 8]);
        #pragma unroll
        for (int j = 0; j < 2; ++j)
            bf[j] = *reinterpret_cast<const short8*>(
                &Bs[(n_off + j * 16 + l16) * AS_STR + quad * 8]);

        #pragma unroll
        for (int i = 0; i < 2; ++i)
            #pragma unroll
            for (int j = 0; j < 2; ++j)
                acc[i][j] = __builtin_amdgcn_mfma_f32_16x16x32_bf16(
                    af[i], bf[j], acc[i][j], 0, 0, 0);
    }

    // epilogue: C/D layout col=lane&15, row=(lane>>4)*4+reg
    const int rb  = (lane >> 4) * 4;
    const int col = l16;
    #pragma unroll
    for (int i = 0; i < 2; ++i)
        #pragma unroll
        for (int j = 0; j < 2; ++j)
            #pragma unroll
            for (int r = 0; r < 4; ++r)
                C[(size_t)(m0 + m_off + i * 16 + rb + r) * N
                  + n0 + n_off + j * 16 + col] = acc[i][j][r];
}

// ---------------------------------------------------------------- windowed attention
// One block (256 threads) per (query s, head h). Window: j in [max(0,s-255), s].
__global__ __launch_bounds__(256) void attn_kernel(const float* __restrict__ qkv,
                                                   unsigned short* __restrict__ outb) {
    const int s   = blockIdx.x;
    const int h   = blockIdx.y;
    const int tid = threadIdx.x;
    const int lane = tid & 63;
    const int wid  = tid >> 6;

    __shared__ float qs[HD];
    __shared__ float p[256];
    __shared__ float wred[4];
    __shared__ float ov[4][HD];

    if (tid < HD) qs[tid] = qkv[(size_t)s * (3 * EMB) + h * HD + tid];
    __syncthreads();

    int js = s - (WIN - 1); if (js < 0) js = 0;
    const int cnt = s - js + 1;  // 1..256

    float score = -1e30f;
    if (tid < cnt) {
        const float* krow = qkv + (size_t)(js + tid) * (3 * EMB) + EMB + h * HD;
        float acc = 0.f;
        #pragma unroll
        for (int d = 0; d < HD; d += 4) {
            float4 k4 = *reinterpret_cast<const float4*>(krow + d);
            acc += qs[d] * k4.x + qs[d + 1] * k4.y + qs[d + 2] * k4.z + qs[d + 3] * k4.w;
        }
        score = acc * SCALE;
    }

    // block max
    float m = score;
    #pragma unroll
    for (int off = 32; off; off >>= 1) m = fmaxf(m, __shfl_xor(m, off, 64));
    if (lane == 0) wred[wid] = m;
    __syncthreads();
    m = fmaxf(fmaxf(wred[0], wred[1]), fmaxf(wred[2], wred[3]));

    float e = (tid < cnt) ? __expf(score - m) : 0.f;
    float ssum = e;
    #pragma unroll
    for (int off = 32; off; off >>= 1) ssum += __shfl_xor(ssum, off, 64);
    __syncthreads();          // protect wred before rewrite
    if (lane == 0) wred[wid] = ssum;
    __syncthreads();
    ssum = wred[0] + wred[1] + wred[2] + wred[3];

    p[tid] = e / ssum;
    __syncthreads();

    // PV: 4 partial waves over keys, 64 dims per wave
    const int d = tid & 63, part = tid >> 6;
    float acc = 0.f;
    const float* vbase = qkv + 2 * EMB + h * HD + d;
    for (int jj = part; jj < cnt; jj += 4)
        acc += p[jj] * vbase[(size_t)(js + jj) * (3 * EMB)];
    ov[part][d] = acc;
    __syncthreads();
    if (part == 0) {
        float r = ov[0][d] + ov[1][d] + ov[2][d] + ov[3][d];
        __hip_bfloat16 b = __float2bfloat16(r);
        outb[(size_t)s * EMB + h * HD + d] = *reinterpret_cast<unsigned short*>(&b);
    }
}

// ---------------------------------------------------------------- launch
extern "C" void kernel_launch(void* const* d_in, const int* in_sizes, int n_in,
                              void* d_out, int out_size, void* d_ws, size_t ws_size,
                              hipStream_t stream) {
    const float* x     = (const float*)d_in[0];
    // d_in[1] = allowed_mask (analytic sliding window — not needed)
    const float* w_qkv = (const float*)d_in[2];
    const float* w_out = (const float*)d_in[3];
    float* out = (float*)d_out;

    char* ws = (char*)d_ws;
    unsigned short* xb    = (unsigned short*)(ws);                       // 4096*1024 bf16 (8 MB)
    unsigned short* wqkvb = (unsigned short*)(ws + (8u << 20));          // 1024*3072 bf16 (6 MB)
    unsigned short* woutb = (unsigned short*)(ws + (14u << 20));         // 1024*1024 bf16 (2 MB)
    float*          qkv   = (float*)(ws + (16u << 20));                  // 4096*3072 f32 (48 MB)
    unsigned short* attnb = (unsigned short*)(ws + (64u << 20));         // 4096*1024 bf16 (8 MB)

    cast_f32_bf16<<<4096, 256, 0, stream>>>(x,     xb,    S_LEN * EMB);
    cast_f32_bf16<<<4096, 256, 0, stream>>>(w_qkv, wqkvb, EMB * 3 * EMB);
    cast_f32_bf16<<<2048, 256, 0, stream>>>(w_out, woutb, EMB * EMB);

    // qkv = x @ w_qkv   [4096,3072]
    gemm_bf16<<<dim3(3 * EMB / 64, S_LEN / 64), 256, 0, stream>>>(
        xb, wqkvb, qkv, S_LEN, 3 * EMB, EMB);

    // windowed attention -> attnb [4096,1024] bf16
    attn_kernel<<<dim3(S_LEN, NH), 256, 0, stream>>>(qkv, attnb);

    // out = attn @ w_out  [4096,1024] f32
    gemm_bf16<<<dim3(EMB / 64, S_LEN / 64), 256, 0, stream>>>(
        attnb, woutb, out, S_LEN, EMB, EMB);
}

// Round 3
// 346.350 us; speedup vs baseline: 3.4031x; 3.4031x over previous
//
#include <hip/hip_runtime.h>
#include <hip/hip_bf16.h>

// Problem constants
#define S_LEN 4096
#define EMB   1024
#define NH    16
#define HD    64
#define WIN   256
#define SCALE 0.125f

typedef __attribute__((ext_vector_type(8))) short short8;   // 8 bf16 (4 VGPRs)
typedef __attribute__((ext_vector_type(4))) float f32x4;    // 4 fp32 acc

__device__ inline unsigned short f2b(float x) {
    __hip_bfloat16 b = __float2bfloat16(x);
    return *reinterpret_cast<unsigned short*>(&b);
}

__device__ inline void pack8(unsigned short* dst, float4 a, float4 b) {
    union { uint4 v; unsigned short u[8]; } t;
    t.u[0] = f2b(a.x); t.u[1] = f2b(a.y); t.u[2] = f2b(a.z); t.u[3] = f2b(a.w);
    t.u[4] = f2b(b.x); t.u[5] = f2b(b.y); t.u[6] = f2b(b.z); t.u[7] = f2b(b.w);
    *reinterpret_cast<uint4*>(dst) = t.v;
}

// ---------------------------------------------------------------- cast f32->bf16
__global__ __launch_bounds__(256) void cast_f32_bf16(const float* __restrict__ in,
                                                     unsigned short* __restrict__ out,
                                                     int n) {
    int i = blockIdx.x * blockDim.x + threadIdx.x;
    int stride = gridDim.x * blockDim.x;
    for (; i < n; i += stride) out[i] = f2b(in[i]);
}

// ---------------------------------------------------------------- bf16 MFMA GEMM
#define AS_STR 56

__global__ __launch_bounds__(256) void gemm_bf16(const unsigned short* __restrict__ A,
                                                 const unsigned short* __restrict__ B,
                                                 float* __restrict__ C,
                                                 int M, int N, int K) {
    __shared__ unsigned short As[64 * AS_STR];
    __shared__ unsigned short Bs[64 * AS_STR];   // transposed: Bs[n][k]

    const int tid  = threadIdx.x;
    const int lane = tid & 63;
    const int wid  = tid >> 6;
    const int quad = lane >> 4;
    const int l16  = lane & 15;

    const int m0 = blockIdx.y * 64;
    const int n0 = blockIdx.x * 64;
    const int m_off = (wid & 1) * 32;
    const int n_off = (wid >> 1) * 32;

    const int a_row = tid >> 2;
    const int a_kc  = (tid & 3) * 8;
    const int b_k  = tid >> 3;
    const int b_n0 = (tid & 7) * 8;

    f32x4 acc[2][2];
    #pragma unroll
    for (int i = 0; i < 2; ++i)
        #pragma unroll
        for (int j = 0; j < 2; ++j)
            acc[i][j] = (f32x4){0.f, 0.f, 0.f, 0.f};

    const int ksteps = K >> 5;
    for (int bk = 0; bk < ksteps; ++bk) {
        __syncthreads();
        {
            const uint4 av = *reinterpret_cast<const uint4*>(
                A + (size_t)(m0 + a_row) * K + bk * 32 + a_kc);
            *reinterpret_cast<uint4*>(&As[a_row * AS_STR + a_kc]) = av;
        }
        {
            union { uint4 v; unsigned short u[8]; } t;
            t.v = *reinterpret_cast<const uint4*>(
                B + (size_t)(bk * 32 + b_k) * N + n0 + b_n0);
            #pragma unroll
            for (int j = 0; j < 8; ++j)
                Bs[(b_n0 + j) * AS_STR + b_k] = t.u[j];
        }
        __syncthreads();

        short8 af[2], bf[2];
        #pragma unroll
        for (int i = 0; i < 2; ++i)
            af[i] = *reinterpret_cast<const short8*>(
                &As[(m_off + i * 16 + l16) * AS_STR + quad * 8]);
        #pragma unroll
        for (int j = 0; j < 2; ++j)
            bf[j] = *reinterpret_cast<const short8*>(
                &Bs[(n_off + j * 16 + l16) * AS_STR + quad * 8]);

        #pragma unroll
        for (int i = 0; i < 2; ++i)
            #pragma unroll
            for (int j = 0; j < 2; ++j)
                acc[i][j] = __builtin_amdgcn_mfma_f32_16x16x32_bf16(
                    af[i], bf[j], acc[i][j], 0, 0, 0);
    }

    const int rb  = (lane >> 4) * 4;
    #pragma unroll
    for (int i = 0; i < 2; ++i)
        #pragma unroll
        for (int j = 0; j < 2; ++j)
            #pragma unroll
            for (int r = 0; r < 4; ++r)
                C[(size_t)(m0 + m_off + i * 16 + rb + r) * N
                  + n0 + n_off + j * 16 + l16] = acc[i][j][r];
}

// ---------------------------------------------------------------- flash MFMA attention
// One block = 64 queries x 1 head. Window union for tile [q0,q0+63] is
// [q0-255, q0+63] -> stage 5 aligned key tiles: [q0-256, q0+63] = 320 keys.
// Each wave owns 16 full query rows -> softmax reductions stay in-wave.
// LDS: Qt[64][72] | Kt[320][72] (aliased later as Pb[64][328]) | Vt[64][328].
#define QT_STR 72
#define PV_STR 328
#define NKEYS  320

__global__ __launch_bounds__(256) void attn_mfma(const float* __restrict__ qkv,
                                                 unsigned short* __restrict__ outb) {
    __shared__ char lds[97280];
    unsigned short* Qt   = (unsigned short*)lds;             // [64][72]    9216 B
    unsigned short* KtPb = (unsigned short*)(lds + 9216);    // Kt [320][72] 46080 B / Pb [64][328]
    unsigned short* Vt   = (unsigned short*)(lds + 55296);   // [64][328]  41984 B

    const int q0   = blockIdx.x * 64;
    const int h    = blockIdx.y;
    const int tid  = threadIdx.x;
    const int w    = tid >> 6;
    const int lane = tid & 63;
    const int quad = lane >> 4;
    const int l16  = lane & 15;
    const int kbase = q0 - 256;

    // ---- stage Q: [64 q][64 d] bf16
    {
        const int row = tid >> 2, db = (tid & 3) * 16;
        const float4* s4 = (const float4*)(qkv + (size_t)(q0 + row) * 3072 + h * 64 + db);
        pack8(&Qt[row * QT_STR + db],     s4[0], s4[1]);
        pack8(&Qt[row * QT_STR + db + 8], s4[2], s4[3]);
    }
    // ---- stage K: [320 k][64 d] bf16 (zero rows for j<0)
    {
        const int rr = tid >> 2, db = (tid & 3) * 16;
        const float4 z = {0.f, 0.f, 0.f, 0.f};
        #pragma unroll
        for (int rg = 0; rg < 5; ++rg) {
            const int kl = rg * 64 + rr;
            const int j  = kbase + kl;
            if (j >= 0) {
                const float4* s4 = (const float4*)(qkv + (size_t)j * 3072 + EMB + h * 64 + db);
                pack8(&KtPb[kl * QT_STR + db],     s4[0], s4[1]);
                pack8(&KtPb[kl * QT_STR + db + 8], s4[2], s4[3]);
            } else {
                pack8(&KtPb[kl * QT_STR + db],     z, z);
                pack8(&KtPb[kl * QT_STR + db + 8], z, z);
            }
        }
    }
    // ---- stage V transposed: Vt[d][k], b32 writes (2 adjacent keys per word)
    {
        const int dg = (tid & 7) * 8;
        const int pr = tid >> 3;             // 0..31 key-pairs per group
        #pragma unroll
        for (int rg = 0; rg < 5; ++rg) {
            const int kl = rg * 64 + pr * 2;
            const int j0 = kbase + kl;       // even, so j0 and j0+1 checks separate
            float v0[8] = {0}, v1[8] = {0};
            if (j0 >= 0) {
                const float4* s = (const float4*)(qkv + (size_t)j0 * 3072 + 2 * EMB + h * 64 + dg);
                float4 a = s[0], b = s[1];
                v0[0]=a.x; v0[1]=a.y; v0[2]=a.z; v0[3]=a.w;
                v0[4]=b.x; v0[5]=b.y; v0[6]=b.z; v0[7]=b.w;
            }
            if (j0 + 1 >= 0) {
                const float4* s = (const float4*)(qkv + (size_t)(j0 + 1) * 3072 + 2 * EMB + h * 64 + dg);
                float4 a = s[0], b = s[1];
                v1[0]=a.x; v1[1]=a.y; v1[2]=a.z; v1[3]=a.w;
                v1[4]=b.x; v1[5]=b.y; v1[6]=b.z; v1[7]=b.w;
            }
            #pragma unroll
            for (int jj = 0; jj < 8; ++jj) {
                unsigned int wv = (unsigned int)f2b(v0[jj]) | ((unsigned int)f2b(v1[jj]) << 16);
                *(unsigned int*)&Vt[(dg + jj) * PV_STR + kl] = wv;
            }
        }
    }
    __syncthreads();

    // ---- QK^T: wave w owns query rows [w*16, w*16+16); cols = all 320 keys
    f32x4 accs[20];
    #pragma unroll
    for (int nb = 0; nb < 20; ++nb) accs[nb] = (f32x4){0.f, 0.f, 0.f, 0.f};

    #pragma unroll
    for (int ks = 0; ks < 2; ++ks) {
        const short8 af = *(const short8*)&Qt[(w * 16 + l16) * QT_STR + ks * 32 + quad * 8];
        #pragma unroll
        for (int nb = 0; nb < 20; ++nb) {
            const short8 bfr = *(const short8*)&KtPb[(nb * 16 + l16) * QT_STR + ks * 32 + quad * 8];
            accs[nb] = __builtin_amdgcn_mfma_f32_16x16x32_bf16(af, bfr, accs[nb], 0, 0, 0);
        }
    }
    __syncthreads();   // all Kt reads done before Pb overwrite

    // ---- softmax (registers; row = quad*4+r, col = nb*16+l16)
    const int i0 = q0 + w * 16 + quad * 4;
    float rmax[4] = {-1e30f, -1e30f, -1e30f, -1e30f};
    #pragma unroll
    for (int nb = 0; nb < 20; ++nb) {
        const int j = kbase + nb * 16 + l16;
        #pragma unroll
        for (int r = 0; r < 4; ++r) {
            const int i = i0 + r;
            const bool ok = (j >= 0) & (j <= i) & (j > i - WIN);
            const float s = accs[nb][r] * SCALE;
            if (ok) rmax[r] = fmaxf(rmax[r], s);
        }
    }
    #pragma unroll
    for (int r = 0; r < 4; ++r)
        #pragma unroll
        for (int off = 1; off < 16; off <<= 1)
            rmax[r] = fmaxf(rmax[r], __shfl_xor(rmax[r], off, 64));

    float rsum[4] = {0.f, 0.f, 0.f, 0.f};
    #pragma unroll
    for (int nb = 0; nb < 20; ++nb) {
        const int j = kbase + nb * 16 + l16;
        #pragma unroll
        for (int r = 0; r < 4; ++r) {
            const int i = i0 + r;
            const bool ok = (j >= 0) & (j <= i) & (j > i - WIN);
            const float e = ok ? __expf(accs[nb][r] * SCALE - rmax[r]) : 0.f;
            rsum[r] += e;
            KtPb[(w * 16 + quad * 4 + r) * PV_STR + nb * 16 + l16] = f2b(e);
        }
    }
    float inv[4];
    #pragma unroll
    for (int r = 0; r < 4; ++r) {
        #pragma unroll
        for (int off = 1; off < 16; off <<= 1)
            rsum[r] += __shfl_xor(rsum[r], off, 64);
        inv[r] = 1.f / rsum[r];
    }
    __syncthreads();

    // ---- PV: O[16 q][64 d] per wave, contraction over 320 keys
    f32x4 acco[4];
    #pragma unroll
    for (int nb2 = 0; nb2 < 4; ++nb2) acco[nb2] = (f32x4){0.f, 0.f, 0.f, 0.f};

    #pragma unroll
    for (int ks = 0; ks < 10; ++ks) {
        const short8 af = *(const short8*)&KtPb[(w * 16 + l16) * PV_STR + ks * 32 + quad * 8];
        #pragma unroll
        for (int nb2 = 0; nb2 < 4; ++nb2) {
            const short8 bfr = *(const short8*)&Vt[(nb2 * 16 + l16) * PV_STR + ks * 32 + quad * 8];
            acco[nb2] = __builtin_amdgcn_mfma_f32_16x16x32_bf16(af, bfr, acco[nb2], 0, 0, 0);
        }
    }

    #pragma unroll
    for (int nb2 = 0; nb2 < 4; ++nb2)
        #pragma unroll
        for (int r = 0; r < 4; ++r)
            outb[(size_t)(q0 + w * 16 + quad * 4 + r) * EMB + h * 64 + nb2 * 16 + l16] =
                f2b(acco[nb2][r] * inv[r]);
}

// ---------------------------------------------------------------- launch
extern "C" void kernel_launch(void* const* d_in, const int* in_sizes, int n_in,
                              void* d_out, int out_size, void* d_ws, size_t ws_size,
                              hipStream_t stream) {
    const float* x     = (const float*)d_in[0];
    const float* w_qkv = (const float*)d_in[2];
    const float* w_out = (const float*)d_in[3];
    float* out = (float*)d_out;

    char* ws = (char*)d_ws;
    unsigned short* xb    = (unsigned short*)(ws);
    unsigned short* wqkvb = (unsigned short*)(ws + (8u << 20));
    unsigned short* woutb = (unsigned short*)(ws + (14u << 20));
    float*          qkv   = (float*)(ws + (16u << 20));
    unsigned short* attnb = (unsigned short*)(ws + (64u << 20));

    cast_f32_bf16<<<4096, 256, 0, stream>>>(x,     xb,    S_LEN * EMB);
    cast_f32_bf16<<<4096, 256, 0, stream>>>(w_qkv, wqkvb, EMB * 3 * EMB);
    cast_f32_bf16<<<2048, 256, 0, stream>>>(w_out, woutb, EMB * EMB);

    gemm_bf16<<<dim3(3 * EMB / 64, S_LEN / 64), 256, 0, stream>>>(
        xb, wqkvb, qkv, S_LEN, 3 * EMB, EMB);

    attn_mfma<<<dim3(S_LEN / 64, NH), 256, 0, stream>>>(qkv, attnb);

    gemm_bf16<<<dim3(EMB / 64, S_LEN / 64), 256, 0, stream>>>(
        attnb, woutb, out, S_LEN, EMB, EMB);
}

// Round 4
// 234.270 us; speedup vs baseline: 5.0312x; 1.4784x over previous
//
#include <hip/hip_runtime.h>
#include <hip/hip_bf16.h>

// Problem constants
#define S_LEN 4096
#define EMB   1024
#define NH    16
#define HD    64
#define WIN   256
#define SCALE 0.125f

typedef __attribute__((ext_vector_type(8))) short short8;   // 8 bf16 (4 VGPRs)
typedef __attribute__((ext_vector_type(4))) float f32x4;    // 4 fp32 acc

__device__ inline unsigned short f2b(float x) {
    __hip_bfloat16 b = __float2bfloat16(x);
    return *reinterpret_cast<unsigned short*>(&b);
}

__device__ inline void gld_lds16(const unsigned short* g, unsigned short* l) {
    __builtin_amdgcn_global_load_lds(
        (const __attribute__((address_space(1))) unsigned int*)g,
        (__attribute__((address_space(3))) unsigned int*)l,
        16, 0, 0);
}

// ---------------------------------------------------------------- cast f32->bf16
__global__ __launch_bounds__(256) void cast_f32_bf16(const float* __restrict__ in,
                                                     unsigned short* __restrict__ out,
                                                     int n) {
    int i = blockIdx.x * blockDim.x + threadIdx.x;
    int stride = gridDim.x * blockDim.x;
    for (; i < n; i += stride) out[i] = f2b(in[i]);
}

// ---------------------------------------------------------------- transpose+cast
// in f32 [R][C] -> out bf16 [C][R].  64x64 tiles; LDS stride 72 (144 B, 16B-mult).
__global__ __launch_bounds__(256) void transpose_cast(const float* __restrict__ in,
                                                      unsigned short* __restrict__ out,
                                                      int R, int C) {
    __shared__ alignas(16) unsigned short t[64 * 72];
    const int tid = threadIdx.x;
    const int r0 = blockIdx.y * 64, c0 = blockIdx.x * 64;

    const int rr = tid >> 4, cc = (tid & 15) * 4;
    #pragma unroll
    for (int i = 0; i < 4; ++i) {
        float4 v = *reinterpret_cast<const float4*>(&in[(size_t)(r0 + rr + i * 16) * C + c0 + cc]);
        t[(cc + 0) * 72 + rr + i * 16] = f2b(v.x);
        t[(cc + 1) * 72 + rr + i * 16] = f2b(v.y);
        t[(cc + 2) * 72 + rr + i * 16] = f2b(v.z);
        t[(cc + 3) * 72 + rr + i * 16] = f2b(v.w);
    }
    __syncthreads();

    const int wr = tid >> 2, wk = (tid & 3) * 16;
    #pragma unroll
    for (int p = 0; p < 2; ++p)
        *reinterpret_cast<uint4*>(&out[(size_t)(c0 + wr) * R + r0 + wk + p * 8]) =
            *reinterpret_cast<const uint4*>(&t[wr * 72 + wk + p * 8]);
}

// ---------------------------------------------------------------- m97-style GEMM
// C[M,N] = A[M,K] @ Bt[N,K]^T, all bf16 in, f32 or bf16 out.
// 128x128 tile, BK=32, 256 threads; wave w owns a 64x64 quadrant (acc[4][4]).
template <bool BF16_OUT>
__global__ __launch_bounds__(256) void gemm_bt(const unsigned short* __restrict__ A,
                                               const unsigned short* __restrict__ Bt,
                                               void* __restrict__ Cout,
                                               int M, int N, int K) {
    __shared__ alignas(16) unsigned short As[128 * 32];   // 8 KB
    __shared__ alignas(16) unsigned short Bs[128 * 32];   // 8 KB

    const int tid  = threadIdx.x;
    const int lane = tid & 63;
    const int w    = tid >> 6;
    const int quad = lane >> 4;
    const int l16  = lane & 15;

    const int m0 = blockIdx.y * 128;
    const int n0 = blockIdx.x * 128;
    const int m_off = (w & 1) * 64;
    const int n_off = (w >> 1) * 64;

    const int srow = tid >> 2;          // 0..63
    const int skof = (tid & 3) * 8;     // k-slot offset in elems

    f32x4 acc[4][4];
    #pragma unroll
    for (int i = 0; i < 4; ++i)
        #pragma unroll
        for (int j = 0; j < 4; ++j)
            acc[i][j] = (f32x4){0.f, 0.f, 0.f, 0.f};

    for (int bk = 0; bk < K; bk += 32) {
        __syncthreads();
        #pragma unroll
        for (int inst = 0; inst < 2; ++inst) {
            gld_lds16(A  + (size_t)(m0 + inst * 64 + srow) * K + bk + skof,
                      As + inst * 2048 + w * 512);
            gld_lds16(Bt + (size_t)(n0 + inst * 64 + srow) * K + bk + skof,
                      Bs + inst * 2048 + w * 512);
        }
        __syncthreads();

        short8 af[4], bf[4];
        #pragma unroll
        for (int i = 0; i < 4; ++i)
            af[i] = *reinterpret_cast<const short8*>(&As[(m_off + i * 16 + l16) * 32 + quad * 8]);
        #pragma unroll
        for (int j = 0; j < 4; ++j)
            bf[j] = *reinterpret_cast<const short8*>(&Bs[(n_off + j * 16 + l16) * 32 + quad * 8]);

        #pragma unroll
        for (int i = 0; i < 4; ++i)
            #pragma unroll
            for (int j = 0; j < 4; ++j)
                acc[i][j] = __builtin_amdgcn_mfma_f32_16x16x32_bf16(
                    af[i], bf[j], acc[i][j], 0, 0, 0);
    }

    // epilogue: C/D layout col=lane&15, row=quad*4+reg
    #pragma unroll
    for (int i = 0; i < 4; ++i)
        #pragma unroll
        for (int r = 0; r < 4; ++r) {
            const size_t row = m0 + m_off + i * 16 + quad * 4 + r;
            #pragma unroll
            for (int j = 0; j < 4; ++j) {
                const size_t idx = row * N + n0 + n_off + j * 16 + l16;
                if (BF16_OUT)
                    ((unsigned short*)Cout)[idx] = f2b(acc[i][j][r]);
                else
                    ((float*)Cout)[idx] = acc[i][j][r];
            }
        }
}

// ---------------------------------------------------------------- flash MFMA attention
// One block = 64 queries x 1 head; keys staged [q0-256, q0+63] = 320 = 5 tiles.
// qkv is bf16 [4096][3072]. Each wave owns 16 full query rows.
// LDS: Qt[64][72] | Kt[320][72] (aliased later as Pb[64][328]) | Vt[64][328].
#define QT_STR 72
#define PV_STR 328

__global__ __launch_bounds__(256) void attn_mfma(const unsigned short* __restrict__ qkv,
                                                 unsigned short* __restrict__ outb) {
    __shared__ char lds[97280];
    unsigned short* Qt   = (unsigned short*)lds;             // [64][72]    9216 B
    unsigned short* KtPb = (unsigned short*)(lds + 9216);    // Kt [320][72] / Pb [64][328]
    unsigned short* Vt   = (unsigned short*)(lds + 55296);   // [64][328]

    const int q0   = blockIdx.x * 64;
    const int h    = blockIdx.y;
    const int tid  = threadIdx.x;
    const int w    = tid >> 6;
    const int lane = tid & 63;
    const int quad = lane >> 4;
    const int l16  = lane & 15;
    const int kbase = q0 - 256;

    // ---- stage Q: [64 q][64 d], pure uint4 copies
    {
        const int c = (tid & 7) * 8;
        #pragma unroll
        for (int p = 0; p < 2; ++p) {
            const int row = (p * 256 + tid) >> 3;
            *reinterpret_cast<uint4*>(&Qt[row * QT_STR + c]) =
                *reinterpret_cast<const uint4*>(&qkv[(size_t)(q0 + row) * 3072 + h * 64 + c]);
        }
    }
    // ---- stage K: [320 k][64 d] (zero rows for j<0)
    {
        const int c = (tid & 7) * 8;
        const uint4 z = {0u, 0u, 0u, 0u};
        #pragma unroll
        for (int p = 0; p < 10; ++p) {
            const int row = (p * 256 + tid) >> 3;
            const int j = kbase + row;
            uint4 v = z;
            if (j >= 0)
                v = *reinterpret_cast<const uint4*>(&qkv[(size_t)j * 3072 + EMB + h * 64 + c]);
            *reinterpret_cast<uint4*>(&KtPb[row * QT_STR + c]) = v;
        }
    }
    // ---- stage V transposed: Vt[d][k], b32 writes (2 adjacent keys per word)
    {
        const int dg = (tid & 7) * 8;
        const int pr = tid >> 3;
        #pragma unroll
        for (int rg = 0; rg < 5; ++rg) {
            const int kl = rg * 64 + pr * 2;
            const int j0 = kbase + kl;
            short8 a = (short8)0, b = (short8)0;
            if (j0 >= 0)
                a = *reinterpret_cast<const short8*>(&qkv[(size_t)j0 * 3072 + 2 * EMB + h * 64 + dg]);
            if (j0 + 1 >= 0)
                b = *reinterpret_cast<const short8*>(&qkv[(size_t)(j0 + 1) * 3072 + 2 * EMB + h * 64 + dg]);
            #pragma unroll
            for (int jj = 0; jj < 8; ++jj) {
                unsigned int wv = (unsigned int)(unsigned short)a[jj]
                                | ((unsigned int)(unsigned short)b[jj] << 16);
                *(unsigned int*)&Vt[(dg + jj) * PV_STR + kl] = wv;
            }
        }
    }
    __syncthreads();

    // ---- QK^T: wave w owns query rows [w*16, w*16+16); cols = all 320 keys
    f32x4 accs[20];
    #pragma unroll
    for (int nb = 0; nb < 20; ++nb) accs[nb] = (f32x4){0.f, 0.f, 0.f, 0.f};

    #pragma unroll
    for (int ks = 0; ks < 2; ++ks) {
        const short8 af = *(const short8*)&Qt[(w * 16 + l16) * QT_STR + ks * 32 + quad * 8];
        #pragma unroll
        for (int nb = 0; nb < 20; ++nb) {
            const short8 bfr = *(const short8*)&KtPb[(nb * 16 + l16) * QT_STR + ks * 32 + quad * 8];
            accs[nb] = __builtin_amdgcn_mfma_f32_16x16x32_bf16(af, bfr, accs[nb], 0, 0, 0);
        }
    }
    __syncthreads();   // all Kt reads done before Pb overwrite

    // ---- softmax (registers; row = quad*4+r, col = nb*16+l16)
    const int i0 = q0 + w * 16 + quad * 4;
    float rmax[4] = {-1e30f, -1e30f, -1e30f, -1e30f};
    #pragma unroll
    for (int nb = 0; nb < 20; ++nb) {
        const int j = kbase + nb * 16 + l16;
        #pragma unroll
        for (int r = 0; r < 4; ++r) {
            const int i = i0 + r;
            const bool ok = (j >= 0) & (j <= i) & (j > i - WIN);
            const float s = accs[nb][r] * SCALE;
            if (ok) rmax[r] = fmaxf(rmax[r], s);
        }
    }
    #pragma unroll
    for (int r = 0; r < 4; ++r)
        #pragma unroll
        for (int off = 1; off < 16; off <<= 1)
            rmax[r] = fmaxf(rmax[r], __shfl_xor(rmax[r], off, 64));

    float rsum[4] = {0.f, 0.f, 0.f, 0.f};
    #pragma unroll
    for (int nb = 0; nb < 20; ++nb) {
        const int j = kbase + nb * 16 + l16;
        #pragma unroll
        for (int r = 0; r < 4; ++r) {
            const int i = i0 + r;
            const bool ok = (j >= 0) & (j <= i) & (j > i - WIN);
            const float e = ok ? __expf(accs[nb][r] * SCALE - rmax[r]) : 0.f;
            rsum[r] += e;
            KtPb[(w * 16 + quad * 4 + r) * PV_STR + nb * 16 + l16] = f2b(e);
        }
    }
    float inv[4];
    #pragma unroll
    for (int r = 0; r < 4; ++r) {
        #pragma unroll
        for (int off = 1; off < 16; off <<= 1)
            rsum[r] += __shfl_xor(rsum[r], off, 64);
        inv[r] = 1.f / rsum[r];
    }
    __syncthreads();

    // ---- PV: O[16 q][64 d] per wave, contraction over 320 keys
    f32x4 acco[4];
    #pragma unroll
    for (int nb2 = 0; nb2 < 4; ++nb2) acco[nb2] = (f32x4){0.f, 0.f, 0.f, 0.f};

    #pragma unroll
    for (int ks = 0; ks < 10; ++ks) {
        const short8 af = *(const short8*)&KtPb[(w * 16 + l16) * PV_STR + ks * 32 + quad * 8];
        #pragma unroll
        for (int nb2 = 0; nb2 < 4; ++nb2) {
            const short8 bfr = *(const short8*)&Vt[(nb2 * 16 + l16) * PV_STR + ks * 32 + quad * 8];
            acco[nb2] = __builtin_amdgcn_mfma_f32_16x16x32_bf16(af, bfr, acco[nb2], 0, 0, 0);
        }
    }

    #pragma unroll
    for (int nb2 = 0; nb2 < 4; ++nb2)
        #pragma unroll
        for (int r = 0; r < 4; ++r)
            outb[(size_t)(q0 + w * 16 + quad * 4 + r) * EMB + h * 64 + nb2 * 16 + l16] =
                f2b(acco[nb2][r] * inv[r]);
}

// ---------------------------------------------------------------- launch
extern "C" void kernel_launch(void* const* d_in, const int* in_sizes, int n_in,
                              void* d_out, int out_size, void* d_ws, size_t ws_size,
                              hipStream_t stream) {
    const float* x     = (const float*)d_in[0];
    const float* w_qkv = (const float*)d_in[2];
    const float* w_out = (const float*)d_in[3];
    float* out = (float*)d_out;

    char* ws = (char*)d_ws;
    unsigned short* xb     = (unsigned short*)(ws);                 // [4096][1024] bf16, 8 MB
    unsigned short* wqkvT  = (unsigned short*)(ws + (8u  << 20));   // [3072][1024] bf16, 6 MB
    unsigned short* woutT  = (unsigned short*)(ws + (14u << 20));   // [1024][1024] bf16, 2 MB
    unsigned short* qkvb   = (unsigned short*)(ws + (16u << 20));   // [4096][3072] bf16, 24 MB
    unsigned short* attnb  = (unsigned short*)(ws + (48u << 20));   // [4096][1024] bf16, 8 MB

    cast_f32_bf16<<<4096, 256, 0, stream>>>(x, xb, S_LEN * EMB);
    transpose_cast<<<dim3(48, 16), 256, 0, stream>>>(w_qkv, wqkvT, EMB, 3 * EMB);
    transpose_cast<<<dim3(16, 16), 256, 0, stream>>>(w_out, woutT, EMB, EMB);

    // qkv = x @ w_qkv  -> bf16 [4096][3072]
    gemm_bt<true><<<dim3(3 * EMB / 128, S_LEN / 128), 256, 0, stream>>>(
        xb, wqkvT, qkvb, S_LEN, 3 * EMB, EMB);

    attn_mfma<<<dim3(S_LEN / 64, NH), 256, 0, stream>>>(qkvb, attnb);

    // out = attn @ w_out -> f32 [4096][1024]
    gemm_bt<false><<<dim3(EMB / 128, S_LEN / 128), 256, 0, stream>>>(
        attnb, woutT, out, S_LEN, EMB, EMB);
}